// Round 4
// baseline (491.799 us; speedup 1.0000x reference)
//
#include <hip/hip_runtime.h>
#include <hip/hip_cooperative_groups.h>
#include <math.h>

namespace cg = cooperative_groups;

// Problem: N=100000 nodes, D=512, E=6400000 edges.
// gate[n] = sigmoid(dot(x[n,:], p) + b)
// out[0:2E)   = float(edge_index)            (tuple output 0, exact in f32)
// out[2E:3E)  = edge_attr[e] * gate[col[e]]  (col = edge_index[E + e])
//
// Traffic floor: read x 204.8 + edge_index 51.2 + edge_attr 25.6 MB,
// write 76.8 + gate 0.4 MB = ~359 MB -> ~57 us at 6.3 TB/s.
// Bench dur_us additionally contains ~290 us of harness reset fills/copies
// (819 MB ws poison alone is ~122 us) -- fixed cost, not addressable here.

// Native clang vector type: __builtin_nontemporal_store requires a vector of
// scalar types, not HIP's struct-wrapped float4.
typedef float fx4 __attribute__((ext_vector_type(4)));

__global__ __launch_bounds__(256) void fused_kernel(
    const float* __restrict__ x,
    const float* __restrict__ p,
    const float* __restrict__ b,
    const int*   __restrict__ edge_index,  // [2*E] int32
    const float* __restrict__ edge_attr,   // [E]
    float*       __restrict__ gate,        // [N] scratch
    float*       __restrict__ out,         // [3*E]
    int N, int E)
{
    const int tid      = blockIdx.x * blockDim.x + threadIdx.x;
    const int nthreads = gridDim.x * blockDim.x;
    const int wave_id  = tid >> 6;
    const int lane     = tid & 63;
    const int nwaves   = nthreads >> 6;

    // ---------------- Phase 1a: per-row matvec + sigmoid ----------------
    // One wave per row; lane reads 32 contiguous bytes -> wave covers the
    // 2 KB row fully coalesced. p (2 KB) stays L1-resident.
    {
        const float bb = b[0];
        const float4* pr = (const float4*)p;
        const float4 p0 = pr[lane * 2];
        const float4 p1 = pr[lane * 2 + 1];
        for (int row = wave_id; row < N; row += nwaves) {
            const float4* xr = (const float4*)(x + (size_t)row * 512);
            float4 x0 = xr[lane * 2];
            float4 x1 = xr[lane * 2 + 1];
            float s = x0.x * p0.x + x0.y * p0.y + x0.z * p0.z + x0.w * p0.w
                    + x1.x * p1.x + x1.y * p1.y + x1.z * p1.z + x1.w * p1.w;
            #pragma unroll
            for (int off = 32; off > 0; off >>= 1)
                s += __shfl_down(s, off, 64);
            if (lane == 0) {
                float t = s + bb;
                gate[row] = 1.0f / (1.0f + __expf(-t));
            }
        }
    }

    const int EV4 = E >> 2;

    // ------- Phase 1b: row0 index conversion (gate-independent) -------
    {
        const int4* row4 = (const int4*)edge_index;
        fx4*        out4 = (fx4*)out;
        for (int i = tid; i < EV4; i += nthreads) {
            int4 v = row4[i];
            fx4 f = { (float)v.x, (float)v.y, (float)v.z, (float)v.w };
            __builtin_nontemporal_store(f, &out4[i]);
        }
    }

    cg::this_grid().sync();

    // ------- Phase 2: col convert + gather + scale -------
    {
        const int4*   col4 = (const int4*)(edge_index + E);
        const float4* ea4  = (const float4*)edge_attr;
        fx4*          outc = ((fx4*)out) + EV4;          // float(col)
        fx4*          outv = (fx4*)(out + 2 * (size_t)E); // values
        for (int i = tid; i < EV4; i += nthreads) {
            int4   c = col4[i];
            float4 a = ea4[i];
            // gathers issued before the dependent math/stores
            float g0 = gate[c.x];
            float g1 = gate[c.y];
            float g2 = gate[c.z];
            float g3 = gate[c.w];
            fx4 cf = { (float)c.x, (float)c.y, (float)c.z, (float)c.w };
            __builtin_nontemporal_store(cf, &outc[i]);
            fx4 r = { a.x * g0, a.y * g1, a.z * g2, a.w * g3 };
            __builtin_nontemporal_store(r, &outv[i]);
        }
    }
}

extern "C" void kernel_launch(void* const* d_in, const int* in_sizes, int n_in,
                              void* d_out, int out_size, void* d_ws, size_t ws_size,
                              hipStream_t stream) {
    const float* x          = (const float*)d_in[0];   // [N, 512]
    const int*   edge_index = (const int*)  d_in[1];   // [2, E] int32 on device
    const float* edge_attr  = (const float*)d_in[2];   // [E]
    const float* p          = (const float*)d_in[3];   // [512, 1]
    const float* b          = (const float*)d_in[4];   // [1]

    const int D = in_sizes[3];            // 512
    int N = in_sizes[0] / D;              // 100000
    int E = in_sizes[2];                  // 6400000

    float* gate = (float*)d_ws;           // N floats = 400 KB scratch
    float* out  = (float*)d_out;

    // 1024 blocks x 256 threads: 4 blocks/CU co-resident. Grid-stride loops
    // cover N rows / E/4 quads.
    void* args[] = { (void*)&x, (void*)&p, (void*)&b, (void*)&edge_index,
                     (void*)&edge_attr, (void*)&gate, (void*)&out,
                     (void*)&N, (void*)&E };
    (void)hipLaunchCooperativeKernel((void*)fused_kernel, dim3(1024), dim3(256),
                                     args, 0, stream);
}